// Round 1
// baseline (66.104 us; speedup 1.0000x reference)
//
#include <hip/hip_runtime.h>

// Agreement routing (capsule dynamic routing), fp32.
// Shapes: preds [B=8,O=32,H=14,W=14,I=32,D=16], b [1,O,H,W,I], out v [B,O,H,W,D].
// One 64-lane wave per (b,o,h,w) site. Lane grid 16 (i-groups) x 4 (d-groups):
//   g_i = lane>>2 owns i in {2*g_i, 2*g_i+1}
//   g_d = lane&3  owns d in [4*g_d, 4*g_d+4)
// preds for a site (512 floats, 2 KB) live in registers for all 4 routing passes.

#define EPSQ 1e-7f

constexpr int NB = 8, NO = 32, NH = 14, NW = 14, NI = 32, ND = 16;
constexpr int SITES = NB * NO * NH * NW;   // 50176
constexpr int OHW   = NO * NH * NW;        // 6272 (b-param sites, shared over batch)

__global__ __launch_bounds__(256) void routing_kernel(
    const float* __restrict__ preds,
    const float* __restrict__ bparam,
    float* __restrict__ out)
{
    const int gtid = blockIdx.x * 256 + threadIdx.x;
    const int site = gtid >> 6;
    const int lane = threadIdx.x & 63;
    if (site >= SITES) return;

    const int g_d = lane & 3;    // d-group: d = 4*g_d + j
    const int g_i = lane >> 2;   // i-group: i = 2*g_i + k

    // ---- load preds fragment: 2 x float4 (rows i=2g_i and 2g_i+1, cols 4g_d..4g_d+3)
    const float* pb = preds + (size_t)site * (NI * ND) + g_i * (2 * ND) + g_d * 4;
    const float4 p0 = *(const float4*)(pb);
    const float4 p1 = *(const float4*)(pb + ND);

    // ---- load routing logits (shared across batch -> L2 broadcast)
    const int sohw = site % OHW;
    const float* bb = bparam + (size_t)sohw * NI + 2 * g_i;
    float b0 = bb[0];
    float b1 = bb[1];

    float c0, c1;          // routing coefficients for this lane's two i's
    float v0, v1, v2, v3;  // v[4*g_d + j], replicated across i-groups after reduce

    // softmax over i (32 values spread as 2 per i-group x 16 i-groups)
    auto softmax_i = [&](float x0, float x1) {
        float m = fmaxf(x0, x1);
        m = fmaxf(m, __shfl_xor(m, 4));
        m = fmaxf(m, __shfl_xor(m, 8));
        m = fmaxf(m, __shfl_xor(m, 16));
        m = fmaxf(m, __shfl_xor(m, 32));
        float e0 = __expf(x0 - m);
        float e1 = __expf(x1 - m);
        float s = e0 + e1;
        s += __shfl_xor(s, 4);
        s += __shfl_xor(s, 8);
        s += __shfl_xor(s, 16);
        s += __shfl_xor(s, 32);
        float r = __frcp_rn(s);
        c0 = e0 * r;
        c1 = e1 * r;
    };

    // s[d] = sum_i c[i]*pred[i][d]; squash -> v
    auto compute_v = [&]() {
        float s0 = c0 * p0.x + c1 * p1.x;
        float s1 = c0 * p0.y + c1 * p1.y;
        float s2 = c0 * p0.z + c1 * p1.z;
        float s3 = c0 * p0.w + c1 * p1.w;
        #pragma unroll
        for (int m = 4; m <= 32; m <<= 1) {
            s0 += __shfl_xor(s0, m);
            s1 += __shfl_xor(s1, m);
            s2 += __shfl_xor(s2, m);
            s3 += __shfl_xor(s3, m);
        }
        float sq = s0 * s0 + s1 * s1 + s2 * s2 + s3 * s3;
        sq += __shfl_xor(sq, 1);
        sq += __shfl_xor(sq, 2);
        const float t = sq / ((1.0f + sq) * sqrtf(sq + EPSQ));
        v0 = t * s0;
        v1 = t * s1;
        v2 = t * s2;
        v3 = t * s3;
    };

    // pass 0
    softmax_i(b0, b1);
    compute_v();

    // 3 routing iterations
    #pragma unroll
    for (int it = 0; it < 3; ++it) {
        float q0 = p0.x * v0 + p0.y * v1 + p0.z * v2 + p0.w * v3;
        float q1 = p1.x * v0 + p1.y * v1 + p1.z * v2 + p1.w * v3;
        q0 += __shfl_xor(q0, 1);
        q0 += __shfl_xor(q0, 2);
        q1 += __shfl_xor(q1, 1);
        q1 += __shfl_xor(q1, 2);
        b0 += q0;
        b1 += q1;
        softmax_i(b0, b1);
        compute_v();
    }

    // epilogue: i-group 0 holds the reduced v; 4 lanes write contiguous 64 B
    if (g_i == 0) {
        *(float4*)(out + (size_t)site * ND + g_d * 4) = make_float4(v0, v1, v2, v3);
    }
}

extern "C" void kernel_launch(void* const* d_in, const int* in_sizes, int n_in,
                              void* d_out, int out_size, void* d_ws, size_t ws_size,
                              hipStream_t stream) {
    const float* preds  = (const float*)d_in[0];
    const float* bparam = (const float*)d_in[1];
    float* out = (float*)d_out;
    const int threads = 256;
    const int blocks = (SITES * 64) / threads;  // 12544
    routing_kernel<<<blocks, threads, 0, stream>>>(preds, bparam, out);
}

// Round 2
// 37.382 us; speedup vs baseline: 1.7683x; 1.7683x over previous
//
#include <hip/hip_runtime.h>

// Capsule agreement routing, fp32.
// preds [B=8,O=32,H=14,W=14,I=32,D=16], b [1,O,H,W,I], out v [B,O,H,W,D].
//
// 4 sites per 64-lane wave: 2 in lane-halves (lane>>5) x 2 interleaved chains.
// Within a 32-lane half: g_i = hl>>2 (8 groups, lane owns i = g_i + 8k, k=0..3),
//                        g_d = hl&3  (4 groups, lane owns d = 4*g_d + j, j=0..3).
// All reductions stay within a 32-lane half: i-reduces use masks {4,8,16}
// (ds_swizzle), d-reduces use masks {1,2} (DPP quad_perm -> plain VALU).
// preds fragment (16 floats/lane/chain) stays in registers for all 4 passes.

#define EPSQ 1e-7f

constexpr int NB = 8, NO = 32, NH = 14, NW = 14, NI = 32, ND = 16;
constexpr int SITES = NB * NO * NH * NW;   // 50176
constexpr int OHW   = NO * NH * NW;        // 6272
constexpr int THREADS = 256;
constexpr int WAVES = SITES / 4;           // 12544 (4 sites per wave)
constexpr int BLOCKS = WAVES * 64 / THREADS; // 3136

__global__ __launch_bounds__(256) void routing_kernel(
    const float* __restrict__ preds,
    const float* __restrict__ bparam,
    float* __restrict__ out)
{
    const int wave = (blockIdx.x * THREADS + threadIdx.x) >> 6;
    const int lane = threadIdx.x & 63;
    const int half = lane >> 5;   // which site of the pair
    const int hl   = lane & 31;
    const int g_d  = hl & 3;      // d = 4*g_d + j
    const int g_i  = hl >> 2;     // i = g_i + 8*k

    float4 p[2][4];   // [chain][k]  pred rows i=g_i+8k, cols 4*g_d..+3
    float  bl[2][4];  // routing logits
    float  cc[2][4];  // routing coefficients
    float  v[2][4];   // v[4*g_d + j], replicated across i-groups

    #pragma unroll
    for (int c = 0; c < 2; ++c) {
        const int s = wave * 4 + c * 2 + half;
        const float* pb = preds + (size_t)s * (NI * ND) + g_i * ND + g_d * 4;
        #pragma unroll
        for (int k = 0; k < 4; ++k)
            p[c][k] = *(const float4*)(pb + k * (8 * ND));   // i = g_i + 8k
        const int sohw = s % OHW;
        const float* bb = bparam + (size_t)sohw * NI + g_i;
        #pragma unroll
        for (int k = 0; k < 4; ++k)
            bl[c][k] = bb[8 * k];
    }

    // softmax over i for one chain (masks 4,8,16 only)
    auto softmax_i = [&](int c) {
        float m = fmaxf(fmaxf(bl[c][0], bl[c][1]), fmaxf(bl[c][2], bl[c][3]));
        m = fmaxf(m, __shfl_xor(m, 4));
        m = fmaxf(m, __shfl_xor(m, 8));
        m = fmaxf(m, __shfl_xor(m, 16));
        float e0 = __expf(bl[c][0] - m);
        float e1 = __expf(bl[c][1] - m);
        float e2 = __expf(bl[c][2] - m);
        float e3 = __expf(bl[c][3] - m);
        float sm = (e0 + e1) + (e2 + e3);
        sm += __shfl_xor(sm, 4);
        sm += __shfl_xor(sm, 8);
        sm += __shfl_xor(sm, 16);
        const float r = __frcp_rn(sm);
        cc[c][0] = e0 * r; cc[c][1] = e1 * r; cc[c][2] = e2 * r; cc[c][3] = e3 * r;
    };

    // s[d] = sum_i c_i p_id, then squash -> v (i-reduce masks 4,8,16; d-reduce 1,2)
    auto compute_v = [&](int c) {
        float s0 = cc[c][0]*p[c][0].x + cc[c][1]*p[c][1].x + cc[c][2]*p[c][2].x + cc[c][3]*p[c][3].x;
        float s1 = cc[c][0]*p[c][0].y + cc[c][1]*p[c][1].y + cc[c][2]*p[c][2].y + cc[c][3]*p[c][3].y;
        float s2 = cc[c][0]*p[c][0].z + cc[c][1]*p[c][1].z + cc[c][2]*p[c][2].z + cc[c][3]*p[c][3].z;
        float s3 = cc[c][0]*p[c][0].w + cc[c][1]*p[c][1].w + cc[c][2]*p[c][2].w + cc[c][3]*p[c][3].w;
        #pragma unroll
        for (int m = 4; m <= 16; m <<= 1) {
            s0 += __shfl_xor(s0, m);
            s1 += __shfl_xor(s1, m);
            s2 += __shfl_xor(s2, m);
            s3 += __shfl_xor(s3, m);
        }
        float sq = s0*s0 + s1*s1 + s2*s2 + s3*s3;
        sq += __shfl_xor(sq, 1);   // DPP quad_perm
        sq += __shfl_xor(sq, 2);   // DPP quad_perm
        const float t = sq / ((1.0f + sq) * sqrtf(sq + EPSQ));
        v[c][0] = t * s0; v[c][1] = t * s1; v[c][2] = t * s2; v[c][3] = t * s3;
    };

    #pragma unroll
    for (int c = 0; c < 2; ++c) softmax_i(c);
    #pragma unroll
    for (int c = 0; c < 2; ++c) compute_v(c);

    #pragma unroll
    for (int it = 0; it < 3; ++it) {
        // agreement: q_i = dot(pred_i, v) over d; d-reduce masks 1,2 (DPP)
        #pragma unroll
        for (int c = 0; c < 2; ++c) {
            #pragma unroll
            for (int k = 0; k < 4; ++k) {
                float q = p[c][k].x*v[c][0] + p[c][k].y*v[c][1]
                        + p[c][k].z*v[c][2] + p[c][k].w*v[c][3];
                q += __shfl_xor(q, 1);
                q += __shfl_xor(q, 2);
                bl[c][k] += q;
            }
        }
        #pragma unroll
        for (int c = 0; c < 2; ++c) softmax_i(c);
        #pragma unroll
        for (int c = 0; c < 2; ++c) compute_v(c);
    }

    // epilogue: i-group 0 of each half writes this half's sites
    if (g_i == 0) {
        #pragma unroll
        for (int c = 0; c < 2; ++c) {
            const int s = wave * 4 + c * 2 + half;
            *(float4*)(out + (size_t)s * ND + g_d * 4) =
                make_float4(v[c][0], v[c][1], v[c][2], v[c][3]);
        }
    }
}

extern "C" void kernel_launch(void* const* d_in, const int* in_sizes, int n_in,
                              void* d_out, int out_size, void* d_ws, size_t ws_size,
                              hipStream_t stream) {
    const float* preds  = (const float*)d_in[0];
    const float* bparam = (const float*)d_in[1];
    float* out = (float*)d_out;
    routing_kernel<<<BLOCKS, THREADS, 0, stream>>>(preds, bparam, out);
}

// Round 3
// 33.814 us; speedup vs baseline: 1.9549x; 1.1055x over previous
//
#include <hip/hip_runtime.h>

// Capsule agreement routing, fp32.
// preds [B=8,O=32,H=14,W=14,I=32,D=16], b [1,O,H,W,I], out v [B,O,H,W,D].
//
// 4 lanes per site; lane q (quad index) owns i in [8q, 8q+8) and ALL 16 d's
// (128 floats of preds in VGPRs, resident for all 4 routing passes).
// The i-partition across lanes is arbitrary (only unordered i-sums are ever
// needed), so:
//   - agreement q_i = sum_d p_id v_d   : fully lane-local
//   - softmax max/sum over i           : 7 lane-local + 2 quad_perm DPP
//   - s_d = sum_i e_i p_id             : lane-local FMA + 2 DPP levels/component
// Zero LDS-pipe instructions: all cross-lane traffic is quad_perm DPP (VALU).

#define EPSQ 1e-7f

constexpr int NI = 32, ND = 16;
constexpr int SITES = 50176;          // 8*32*14*14
constexpr int OHW   = 6272;           // 32*14*14
constexpr int THREADS = 256;
constexpr int BLOCKS  = SITES * 4 / THREADS;   // 784

__device__ __forceinline__ float dpp_xor1(float x) {
    return __int_as_float(__builtin_amdgcn_mov_dpp(__float_as_int(x), 0xB1, 0xF, 0xF, true));
}
__device__ __forceinline__ float dpp_xor2(float x) {
    return __int_as_float(__builtin_amdgcn_mov_dpp(__float_as_int(x), 0x4E, 0xF, 0xF, true));
}

__device__ __forceinline__ void fma4(float4& a, float c, const float4& x) {
    a.x = fmaf(c, x.x, a.x); a.y = fmaf(c, x.y, a.y);
    a.z = fmaf(c, x.z, a.z); a.w = fmaf(c, x.w, a.w);
}
__device__ __forceinline__ float dot4(const float4& a, const float4& b) {
    return fmaf(a.x, b.x, fmaf(a.y, b.y, fmaf(a.z, b.z, a.w * b.w)));
}
// quad all-reduce (sum) of a float4, component-wise, via DPP quad_perm
__device__ __forceinline__ void qred4(float4& a) {
    a.x += dpp_xor1(a.x); a.y += dpp_xor1(a.y);
    a.z += dpp_xor1(a.z); a.w += dpp_xor1(a.w);
    a.x += dpp_xor2(a.x); a.y += dpp_xor2(a.y);
    a.z += dpp_xor2(a.z); a.w += dpp_xor2(a.w);
}

__global__ __launch_bounds__(256, 2) void routing_kernel(
    const float* __restrict__ preds,
    const float* __restrict__ bparam,
    float* __restrict__ out)
{
    const int tid  = blockIdx.x * THREADS + threadIdx.x;
    const int site = tid >> 2;
    const int q    = tid & 3;

    // ---- load preds fragment: rows i = 8q..8q+7, all 16 d (contiguous 512 B/lane)
    const float4* pb = (const float4*)(preds + (size_t)site * (NI * ND) + q * (8 * ND));
    float4 p[8][4];
    #pragma unroll
    for (int k = 0; k < 8; ++k)
        #pragma unroll
        for (int j = 0; j < 4; ++j)
            p[k][j] = pb[k * 4 + j];

    // ---- routing logits for this lane's 8 i's
    const int sohw = site % OHW;
    const float4* bb = (const float4*)(bparam + (size_t)sohw * NI + q * 8);
    float bl[8];
    {
        float4 t0 = bb[0], t1 = bb[1];
        bl[0] = t0.x; bl[1] = t0.y; bl[2] = t0.z; bl[3] = t0.w;
        bl[4] = t1.x; bl[5] = t1.y; bl[6] = t1.z; bl[7] = t1.w;
    }

    float4 v0, v1, v2, v3;   // v[0..15], replicated across the quad after reduce

    auto pass = [&]() {
        // softmax over 32 i's: 8 lane-local + quad reduce
        float m = bl[0];
        #pragma unroll
        for (int k = 1; k < 8; ++k) m = fmaxf(m, bl[k]);
        m = fmaxf(m, dpp_xor1(m));
        m = fmaxf(m, dpp_xor2(m));
        float e[8];
        float sm = 0.0f;
        #pragma unroll
        for (int k = 0; k < 8; ++k) { e[k] = __expf(bl[k] - m); sm += e[k]; }
        sm += dpp_xor1(sm);
        sm += dpp_xor2(sm);
        const float r = __frcp_rn(sm);   // quad-uniform

        // s~_d = sum_{i local} e_i p_id, quad-reduce, then scale by r
        float4 s0 = {0,0,0,0}, s1 = {0,0,0,0}, s2 = {0,0,0,0}, s3 = {0,0,0,0};
        #pragma unroll
        for (int k = 0; k < 8; ++k) {
            fma4(s0, e[k], p[k][0]);
            fma4(s1, e[k], p[k][1]);
            fma4(s2, e[k], p[k][2]);
            fma4(s3, e[k], p[k][3]);
        }
        qred4(s0); qred4(s1); qred4(s2); qred4(s3);
        s0.x *= r; s0.y *= r; s0.z *= r; s0.w *= r;
        s1.x *= r; s1.y *= r; s1.z *= r; s1.w *= r;
        s2.x *= r; s2.y *= r; s2.z *= r; s2.w *= r;
        s3.x *= r; s3.y *= r; s3.z *= r; s3.w *= r;

        // squash (fully lane-local; s is replicated)
        const float sq = dot4(s0, s0) + dot4(s1, s1) + dot4(s2, s2) + dot4(s3, s3);
        const float t  = sq / ((1.0f + sq) * sqrtf(sq + EPSQ));
        v0.x = t * s0.x; v0.y = t * s0.y; v0.z = t * s0.z; v0.w = t * s0.w;
        v1.x = t * s1.x; v1.y = t * s1.y; v1.z = t * s1.z; v1.w = t * s1.w;
        v2.x = t * s2.x; v2.y = t * s2.y; v2.z = t * s2.z; v2.w = t * s2.w;
        v3.x = t * s3.x; v3.y = t * s3.y; v3.z = t * s3.z; v3.w = t * s3.w;
    };

    pass();

    #pragma unroll
    for (int it = 0; it < 3; ++it) {
        // agreement: q_i = dot(p_i, v) — fully lane-local
        #pragma unroll
        for (int k = 0; k < 8; ++k) {
            bl[k] += dot4(p[k][0], v0) + dot4(p[k][1], v1)
                   + dot4(p[k][2], v2) + dot4(p[k][3], v3);
        }
        pass();
    }

    // epilogue: v replicated across quad; lane q writes component block q
    const float4 w = (q == 0) ? v0 : (q == 1) ? v1 : (q == 2) ? v2 : v3;
    *(float4*)(out + (size_t)site * ND + q * 4) = w;
}

extern "C" void kernel_launch(void* const* d_in, const int* in_sizes, int n_in,
                              void* d_out, int out_size, void* d_ws, size_t ws_size,
                              hipStream_t stream) {
    const float* preds  = (const float*)d_in[0];
    const float* bparam = (const float*)d_in[1];
    float* out = (float*)d_out;
    routing_kernel<<<BLOCKS, THREADS, 0, stream>>>(preds, bparam, out);
}

// Round 4
// 27.642 us; speedup vs baseline: 2.3914x; 1.2233x over previous
//
#include <hip/hip_runtime.h>

// Capsule agreement routing, fp32.
// preds [8,32,14,14,32,16], b [1,32,14,14,32], out v [8,32,14,14,16].
//
// 16 sites per 64-lane wave; lane (s_w = lane>>2, q = lane&3) owns rows
// i in [8q, 8q+8) x all 16 d of site s_w (128 floats resident in VGPRs).
//
// Global loads are perfectly coalesced (each instr = contiguous 1 KB/wave);
// ownership layout is produced by an XOR-swizzled LDS round-trip:
//   chunk c (float4 index, 0..127) of within-wave site x stored at
//   LDS slot x*128 + (c ^ x)   -> both ds_write and ds_read conflict-free.
// Wave-synchronous staging (each wave uses its own 16 KB slice, staged in
// two 8-site halves): s_waitcnt lgkmcnt(0) only, no __syncthreads.
//
// Algorithm per pass (all cross-lane = quad_perm DPP, zero LDS-pipe ops):
//   softmax over i: no max-sub (|b| <= ~36 -> exp fp32-safe), partial sums
//     + 2 DPP; normalization r folded into the squash scale.
//   s~_d = sum_i e_i p_id : lane-local FMA + quad-reduce (2 DPP/comp).
//   squash: lane-local on replicated s~, with |s|^2 = r^2 |s~|^2.
//   agreement q_i = dot(p_i, v): fully lane-local (lane owns full rows).

#define EPSQ 1e-7f

constexpr int NI = 32, ND = 16;
constexpr int SITES = 50176;          // 8*32*14*14
constexpr int OHW   = 6272;           // 32*14*14
constexpr int THREADS = 256;
constexpr int BLOCKS  = SITES / 64;   // 784 (16 sites/wave * 4 waves/block)

__device__ __forceinline__ float dpp_xor1(float x) {
    return __int_as_float(__builtin_amdgcn_mov_dpp(__float_as_int(x), 0xB1, 0xF, 0xF, true));
}
__device__ __forceinline__ float dpp_xor2(float x) {
    return __int_as_float(__builtin_amdgcn_mov_dpp(__float_as_int(x), 0x4E, 0xF, 0xF, true));
}
__device__ __forceinline__ void fma4(float4& a, float c, const float4& x) {
    a.x = fmaf(c, x.x, a.x); a.y = fmaf(c, x.y, a.y);
    a.z = fmaf(c, x.z, a.z); a.w = fmaf(c, x.w, a.w);
}
__device__ __forceinline__ float dot4(const float4& a, const float4& b) {
    return fmaf(a.x, b.x, fmaf(a.y, b.y, fmaf(a.z, b.z, a.w * b.w)));
}
__device__ __forceinline__ void qred4(float4& a) {
    a.x += dpp_xor1(a.x); a.y += dpp_xor1(a.y);
    a.z += dpp_xor1(a.z); a.w += dpp_xor1(a.w);
    a.x += dpp_xor2(a.x); a.y += dpp_xor2(a.y);
    a.z += dpp_xor2(a.z); a.w += dpp_xor2(a.w);
}

__global__ __launch_bounds__(256, 2) void routing_kernel(
    const float* __restrict__ preds,
    const float* __restrict__ bparam,
    float* __restrict__ out)
{
    __shared__ float4 lds4[4096];     // 64 KB = 4 waves x 16 KB
    const int tid  = threadIdx.x;
    const int lane = tid & 63;
    const int wib  = tid >> 6;
    const int wave = blockIdx.x * 4 + wib;
    const int q    = lane & 3;
    const int s_w  = lane >> 2;       // within-wave site 0..15
    const int site = wave * 16 + s_w;

    float4* wlds = lds4 + wib * 1024;
    const float4* pg = (const float4*)preds + (size_t)wave * 2048;

    // ---- coalesced global loads: each instr = 64 consecutive float4s (1 KB)
    float4 t0[16], t1[16];
    #pragma unroll
    for (int k = 0; k < 16; ++k) t0[k] = pg[k * 64 + lane];
    #pragma unroll
    for (int k = 0; k < 16; ++k) t1[k] = pg[1024 + k * 64 + lane];

    // ---- routing logits for this lane's 8 rows (L2-resident, reused 8x)
    const int sohw = site % OHW;
    const float4* bb4 = (const float4*)(bparam + (size_t)sohw * NI + q * 8);
    const float4 bA = bb4[0], bB = bb4[1];
    float bl[8] = {bA.x, bA.y, bA.z, bA.w, bB.x, bB.y, bB.z, bB.w};

    float4 p[8][4];
    const int cb = 32 * q;            // lane's chunk base within its site

    // ---- stage half 0 (within-wave sites 0..7) ----
    #pragma unroll
    for (int k = 0; k < 16; ++k) {
        const int x = k >> 1;                         // site-local 0..7
        wlds[x * 128 + ((((k & 1) * 64) + lane) ^ x)] = t0[k];
    }
    asm volatile("s_waitcnt lgkmcnt(0)" ::: "memory");
    if (s_w < 8) {
        const int x = s_w;
        #pragma unroll
        for (int r = 0; r < 8; ++r)
            #pragma unroll
            for (int u = 0; u < 4; ++u)
                p[r][u] = wlds[x * 128 + ((cb + 4 * r + u) ^ x)];
    }
    asm volatile("s_waitcnt lgkmcnt(0)" ::: "memory");   // reads drained before reuse
    // ---- stage half 1 (within-wave sites 8..15), buffer reused ----
    #pragma unroll
    for (int k = 0; k < 16; ++k) {
        const int x = k >> 1;
        wlds[x * 128 + ((((k & 1) * 64) + lane) ^ x)] = t1[k];
    }
    asm volatile("s_waitcnt lgkmcnt(0)" ::: "memory");
    if (s_w >= 8) {
        const int x = s_w - 8;
        #pragma unroll
        for (int r = 0; r < 8; ++r)
            #pragma unroll
            for (int u = 0; u < 4; ++u)
                p[r][u] = wlds[x * 128 + ((cb + 4 * r + u) ^ x)];
    }

    float4 v0, v1, v2, v3;            // v[0..15], replicated across the quad

    auto pass = [&]() {
        // softmax over 32 i's, no max-sub; 8 lane-local exps + quad reduce
        float e[8];
        float sm = 0.0f;
        #pragma unroll
        for (int k = 0; k < 8; ++k) { e[k] = __expf(bl[k]); sm += e[k]; }
        sm += dpp_xor1(sm);
        sm += dpp_xor2(sm);
        const float r = __frcp_rn(sm);

        // unnormalized s~_d = sum_i e_i p_id, quad-reduced
        float4 s0 = {0,0,0,0}, s1 = {0,0,0,0}, s2 = {0,0,0,0}, s3 = {0,0,0,0};
        #pragma unroll
        for (int k = 0; k < 8; ++k) {
            fma4(s0, e[k], p[k][0]); fma4(s1, e[k], p[k][1]);
            fma4(s2, e[k], p[k][2]); fma4(s3, e[k], p[k][3]);
        }
        qred4(s0); qred4(s1); qred4(s2); qred4(s3);

        // squash with normalization folded: |s|^2 = r^2 |s~|^2, v = f * s~
        const float sqt = dot4(s0, s0) + dot4(s1, s1) + dot4(s2, s2) + dot4(s3, s3);
        const float sq  = r * r * sqt;
        const float f   = sq * __frcp_rn(1.0f + sq) * __frsqrt_rn(sq + EPSQ) * r;
        v0.x = f*s0.x; v0.y = f*s0.y; v0.z = f*s0.z; v0.w = f*s0.w;
        v1.x = f*s1.x; v1.y = f*s1.y; v1.z = f*s1.z; v1.w = f*s1.w;
        v2.x = f*s2.x; v2.y = f*s2.y; v2.z = f*s2.z; v2.w = f*s2.w;
        v3.x = f*s3.x; v3.y = f*s3.y; v3.z = f*s3.z; v3.w = f*s3.w;
    };

    pass();

    #pragma unroll
    for (int it = 0; it < 3; ++it) {
        // agreement: q_i = dot(p_i, v) over all 16 d — fully lane-local
        #pragma unroll
        for (int k = 0; k < 8; ++k) {
            bl[k] += dot4(p[k][0], v0) + dot4(p[k][1], v1)
                   + dot4(p[k][2], v2) + dot4(p[k][3], v3);
        }
        pass();
    }

    // epilogue: v replicated across quad; all 64 lanes write one float4
    // -> per wave a contiguous 1 KB store burst
    float4 w = (q == 0) ? v0 : (q == 1) ? v1 : (q == 2) ? v2 : v3;
    ((float4*)out)[(size_t)site * 4 + q] = w;
}

extern "C" void kernel_launch(void* const* d_in, const int* in_sizes, int n_in,
                              void* d_out, int out_size, void* d_ws, size_t ws_size,
                              hipStream_t stream) {
    const float* preds  = (const float*)d_in[0];
    const float* bparam = (const float*)d_in[1];
    float* out = (float*)d_out;
    routing_kernel<<<BLOCKS, THREADS, 0, stream>>>(preds, bparam, out);
}